// Round 3
// baseline (2158.944 us; speedup 1.0000x reference)
//
#include <hip/hip_runtime.h>

// IntersiteModel fused kernel — fp32 vector, round 5: spill-free restructure.
// Post-mortem r3/r4: 302MB scratch writes at VGPR=128; allocator budget is
// ~128 and weight rows stream through VGPRs. Fix: keep peak live < ~120.
//   * u0 computed in halves (32 regs); s-half folded into acc0 immediately
//     (full-unroll 32x32, static indices); g-half parked (32 regs).
//   * u1 computed per-component i (32 regs) in a rolled i-loop; gated and
//     contracted against W3_11 immediately (full-unroll, static). Per-pass
//     e1 components re-loaded from global (L2-hot) — avoids runtime-indexed
//     register arrays (scratch demotion).
//   * every contraction nest: outer v static (unrolled 4), inner u rolled
//     (#pragma unroll 1) -> exactly ONE 32-float weight row in flight.
//   * stage 1 de-factored (W1_01/W1_10 direct): peak t0(32)+t1(48)+row(16).
// LDS per-thread column (f*128+tid), 80 floats -> 40KB/block, 4 blocks/CU,
// no barriers anywhere (strictly per-thread columns).

#define TPB 128

__device__ __forceinline__ float sigf(float x) {
    return 1.0f / (1.0f + __expf(-x));
}

__global__ __launch_bounds__(TPB, 2)
void intersite_fused(const float* __restrict__ site1,
                     const float* __restrict__ site2,
                     const float* __restrict__ edge,
                     const float* __restrict__ W1_00,
                     const float* __restrict__ W1_11_0,
                     const float* __restrict__ W1_01,
                     const float* __restrict__ W1_10,
                     const float* __restrict__ W1_11_1,
                     const float* __restrict__ W2_00,
                     const float* __restrict__ W2_11_0,
                     const float* __restrict__ W2_01,
                     const float* __restrict__ W2_10,
                     const float* __restrict__ W2_11_1,
                     const float* __restrict__ W3_00,
                     const float* __restrict__ W3_11,
                     float* __restrict__ out, int B)
{
    __shared__ float lds[80 * TPB];
    const int t = threadIdx.x;
    const int b = blockIdx.x * TPB + t;
    if (b >= B) return;   // no barriers anywhere -> early return is safe

#define LDSF(f) lds[(f) * TPB + t]

    const float inv_s3   = 0.57735026918962576f;  // 1/sqrt(3)
    const float inv_s2   = 0.70710678118654752f;  // 1/sqrt(2)
    const float inv_s320 = 0.05590169943749474f;  // 1/sqrt(320)
    const float inv_s192 = 0.07216878364870323f;  // 1/sqrt(192)
    const float inv_s256 = 0.0625f;               // 1/sqrt(256)
    const float inv_s2048= 0.02209708691207961f;  // 1/sqrt(2048)

    // ---------------- stage inputs into LDS ----------------
    // f 0..15 x0 | f 16..39 x1[u*3+i] | f 40..55 y0 | f 56..79 y1[v*3+i]
    {
        const float4* p1 = (const float4*)(site1 + (size_t)b * 40);
        #pragma unroll
        for (int q = 0; q < 10; ++q) {
            float4 r = p1[q];
            LDSF(q*4+0) = r.x; LDSF(q*4+1) = r.y;
            LDSF(q*4+2) = r.z; LDSF(q*4+3) = r.w;
        }
        const float4* p2 = (const float4*)(site2 + (size_t)b * 40);
        #pragma unroll
        for (int q = 0; q < 10; ++q) {
            float4 r = p2[q];
            LDSF(40+q*4+0) = r.x; LDSF(40+q*4+1) = r.y;
            LDSF(40+q*4+2) = r.z; LDSF(40+q*4+3) = r.w;
        }
    }

    // ---------------- stage 1a: t0[32] ----------------
    float t0[32];
    #pragma unroll
    for (int k = 0; k < 32; ++k) t0[k] = 0.0f;

    // W1_00 (16,16,32): t0[w] += x0[u] y0[v] W[u,v,w]
    #pragma unroll 1
    for (int uv = 0; uv < 256; ++uv) {
        float f = LDSF(uv >> 4) * LDSF(40 + (uv & 15));
        const float* w = W1_00 + uv * 32;
        #pragma unroll
        for (int k = 0; k < 32; ++k) t0[k] = fmaf(f, w[k], t0[k]);
    }
    // W1_11_0 (8,8,32): t0[w] += (x1[u].y1[v])/sqrt3 W[u,v,w]
    #pragma unroll 1
    for (int uv = 0; uv < 64; ++uv) {
        int u = uv >> 3, v = uv & 7;
        float d =          LDSF(16+u*3)   * LDSF(56+v*3);
        d = fmaf(LDSF(17+u*3), LDSF(57+v*3), d);
        d = fmaf(LDSF(18+u*3), LDSF(58+v*3), d);
        d *= inv_s3;
        const float* w = W1_11_0 + uv * 32;
        #pragma unroll
        for (int k = 0; k < 32; ++k) t0[k] = fmaf(d, w[k], t0[k]);
    }
    #pragma unroll
    for (int k = 0; k < 32; ++k) t0[k] *= inv_s320;

    // ---------------- stage 1b: t1[16][3] (t0 parked, 80 live) ----------------
    float t1[48];
    #pragma unroll
    for (int j = 0; j < 48; ++j) t1[j] = 0.0f;

    // W1_01 (16,8,16) direct: t1[w,i] += x0[u] y1[v,i] W[u,v,w]
    #pragma unroll 1
    for (int uv = 0; uv < 128; ++uv) {
        int u = uv >> 3, v = uv & 7;
        float xu = LDSF(u);
        float f0 = xu * LDSF(56+v*3+0);
        float f1 = xu * LDSF(56+v*3+1);
        float f2 = xu * LDSF(56+v*3+2);
        const float* w = W1_01 + u*128 + v*16;   // u*8*16 + v*16
        #pragma unroll
        for (int k = 0; k < 16; ++k) {
            t1[k*3+0] = fmaf(f0, w[k], t1[k*3+0]);
            t1[k*3+1] = fmaf(f1, w[k], t1[k*3+1]);
            t1[k*3+2] = fmaf(f2, w[k], t1[k*3+2]);
        }
    }
    // W1_10 (8,16,16) direct: t1[w,i] += x1[u,i] y0[v] W[u,v,w]
    #pragma unroll 1
    for (int uv = 0; uv < 128; ++uv) {
        int u = uv >> 4, v = uv & 15;
        float yv = LDSF(40 + v);
        float f0 = yv * LDSF(16+u*3+0);
        float f1 = yv * LDSF(16+u*3+1);
        float f2 = yv * LDSF(16+u*3+2);
        const float* w = W1_10 + u*256 + v*16;   // u*16*16 + v*16
        #pragma unroll
        for (int k = 0; k < 16; ++k) {
            t1[k*3+0] = fmaf(f0, w[k], t1[k*3+0]);
            t1[k*3+1] = fmaf(f1, w[k], t1[k*3+1]);
            t1[k*3+2] = fmaf(f2, w[k], t1[k*3+2]);
        }
    }
    // W1_11_1 (8,8,16): t1[w,i] += (x1[u] x y1[v])_i / sqrt2 * W[u,v,w]
    #pragma unroll 1
    for (int uv = 0; uv < 64; ++uv) {
        int u = uv >> 3, v = uv & 7;
        float ax = LDSF(16+u*3), ay = LDSF(17+u*3), az = LDSF(18+u*3);
        float bx = LDSF(56+v*3), by = LDSF(57+v*3), bz = LDSF(58+v*3);
        float cx = (ay*bz - az*by) * inv_s2;
        float cy = (az*bx - ax*bz) * inv_s2;
        float cz = (ax*by - ay*bx) * inv_s2;
        const float* w = W1_11_1 + uv * 16;
        #pragma unroll
        for (int k = 0; k < 16; ++k) {
            t1[k*3+0] = fmaf(cx, w[k], t1[k*3+0]);
            t1[k*3+1] = fmaf(cy, w[k], t1[k*3+1]);
            t1[k*3+2] = fmaf(cz, w[k], t1[k*3+2]);
        }
    }
    #pragma unroll
    for (int j = 0; j < 48; ++j) t1[j] *= inv_s320;

    // handoff: x/y dead; f 0..31 = t0, f 32..79 = t1; t regs die here
    #pragma unroll
    for (int k = 0; k < 32; ++k) LDSF(k) = t0[k];
    #pragma unroll
    for (int j = 0; j < 48; ++j) LDSF(32 + j) = t1[j];

    // ---------------- edge -> regs (first use is stage 2) ----------------
    float e0r[4], e1r[12];
    {
        const float4* pe = (const float4*)(edge + (size_t)b * 16);
        float4 r0 = pe[0], r1 = pe[1], r2 = pe[2], r3 = pe[3];
        e0r[0]=r0.x; e0r[1]=r0.y; e0r[2]=r0.z; e0r[3]=r0.w;
        e1r[0]=r1.x; e1r[1]=r1.y; e1r[2]=r1.z; e1r[3]=r1.w;
        e1r[4]=r2.x; e1r[5]=r2.y; e1r[6]=r2.z; e1r[7]=r2.w;
        e1r[8]=r3.x; e1r[9]=r3.y; e1r[10]=r3.z; e1r[11]=r3.w;
    }

    float acc0 = 0.0f;
    // ---------------- stage 2a: u0 low half -> s -> acc0 ----------------
    {
        float ua[32];
        #pragma unroll
        for (int k = 0; k < 32; ++k) ua[k] = 0.0f;
        // W2_00 (32,4,64), k in [0,32)
        #pragma unroll
        for (int v = 0; v < 4; ++v) {
            #pragma unroll 1
            for (int u = 0; u < 32; ++u) {
                float f = LDSF(u) * e0r[v];
                const float* w = W2_00 + u*256 + v*64;
                #pragma unroll
                for (int k = 0; k < 32; ++k) ua[k] = fmaf(f, w[k], ua[k]);
            }
        }
        // W2_11_0 (16,4,64), k in [0,32)
        #pragma unroll
        for (int v = 0; v < 4; ++v) {
            #pragma unroll 1
            for (int u = 0; u < 16; ++u) {
                float d =          LDSF(32+u*3)   * e1r[v*3];
                d = fmaf(LDSF(33+u*3), e1r[v*3+1], d);
                d = fmaf(LDSF(34+u*3), e1r[v*3+2], d);
                d *= inv_s3;
                const float* w = W2_11_0 + u*256 + v*64;
                #pragma unroll
                for (int k = 0; k < 32; ++k) ua[k] = fmaf(d, w[k], ua[k]);
            }
        }
        // s = silu(ua/sqrt192); acc0 = s^T W3_00 s (full unroll, static)
        #pragma unroll
        for (int k = 0; k < 32; ++k) {
            float x = ua[k] * inv_s192;
            ua[k] = x * sigf(x);
        }
        #pragma unroll
        for (int u = 0; u < 32; ++u) {
            const float* w = W3_00 + u*32;
            float row = 0.0f;
            #pragma unroll
            for (int k = 0; k < 32; ++k) row = fmaf(ua[k], w[k], row);
            acc0 = fmaf(ua[u], row, acc0);
        }
    }

    // ---------------- stage 2a': u0 high half -> g[32] ----------------
    float g[32];
    {
        float ub[32];
        #pragma unroll
        for (int k = 0; k < 32; ++k) ub[k] = 0.0f;
        #pragma unroll
        for (int v = 0; v < 4; ++v) {
            #pragma unroll 1
            for (int u = 0; u < 32; ++u) {
                float f = LDSF(u) * e0r[v];
                const float* w = W2_00 + u*256 + v*64 + 32;
                #pragma unroll
                for (int k = 0; k < 32; ++k) ub[k] = fmaf(f, w[k], ub[k]);
            }
        }
        #pragma unroll
        for (int v = 0; v < 4; ++v) {
            #pragma unroll 1
            for (int u = 0; u < 16; ++u) {
                float d =          LDSF(32+u*3)   * e1r[v*3];
                d = fmaf(LDSF(33+u*3), e1r[v*3+1], d);
                d = fmaf(LDSF(34+u*3), e1r[v*3+2], d);
                d *= inv_s3;
                const float* w = W2_11_0 + u*256 + v*64 + 32;
                #pragma unroll
                for (int k = 0; k < 32; ++k) ub[k] = fmaf(d, w[k], ub[k]);
            }
        }
        #pragma unroll
        for (int k = 0; k < 32; ++k) g[k] = sigf(ub[k] * inv_s192);
    }

    // ---------------- stage 2b+3: per-component u1_i -> gate -> acc1 -------
    // rolled i-loop; e1 components re-loaded from global per pass (L2-hot)
    // so no register array is ever runtime-indexed.
    float acc1 = 0.0f;
    const float* ep = edge + (size_t)b * 16 + 4;
    #pragma unroll 1
    for (int i = 0; i < 3; ++i) {
        int jj = (i == 2) ? 0 : i + 1;
        int kk = (jj == 2) ? 0 : jj + 1;
        float u1i[32];
        #pragma unroll
        for (int k = 0; k < 32; ++k) u1i[k] = 0.0f;

        // W2_01 (32,4,32): u1_i[w] += t0[u] e1[v,i] W[u,v,w]
        float e1i[4];
        #pragma unroll
        for (int v = 0; v < 4; ++v) e1i[v] = ep[v*3 + i];
        #pragma unroll
        for (int v = 0; v < 4; ++v) {
            #pragma unroll 1
            for (int u = 0; u < 32; ++u) {
                float f = LDSF(u) * e1i[v];
                const float* w = W2_01 + u*128 + v*32;
                #pragma unroll
                for (int k = 0; k < 32; ++k) u1i[k] = fmaf(f, w[k], u1i[k]);
            }
        }
        // W2_10 (16,4,32): u1_i[w] += t1[u,i] e0[v] W[u,v,w]
        #pragma unroll
        for (int v = 0; v < 4; ++v) {
            #pragma unroll 1
            for (int u = 0; u < 16; ++u) {
                float f = LDSF(32 + u*3 + i) * e0r[v];
                const float* w = W2_10 + u*128 + v*32;
                #pragma unroll
                for (int k = 0; k < 32; ++k) u1i[k] = fmaf(f, w[k], u1i[k]);
            }
        }
        // W2_11_1 (16,4,32): u1_i[w] += (t1[u] x e1[v])_i /sqrt2 W[u,v,w]
        float e1j[4], e1k[4];
        #pragma unroll
        for (int v = 0; v < 4; ++v) { e1j[v] = ep[v*3 + jj]; e1k[v] = ep[v*3 + kk]; }
        #pragma unroll
        for (int v = 0; v < 4; ++v) {
            #pragma unroll 1
            for (int u = 0; u < 16; ++u) {
                float c = (LDSF(32+u*3+jj) * e1k[v] - LDSF(32+u*3+kk) * e1j[v]) * inv_s2;
                const float* w = W2_11_1 + u*128 + v*32;
                #pragma unroll
                for (int k = 0; k < 32; ++k) u1i[k] = fmaf(c, w[k], u1i[k]);
            }
        }
        // gate: v_i = (u1_i/sqrt256) * g ; acc1 += v_i^T W3_11 v_i (static)
        #pragma unroll
        for (int k = 0; k < 32; ++k) u1i[k] = u1i[k] * inv_s256 * g[k];
        #pragma unroll
        for (int u = 0; u < 32; ++u) {
            const float* w = W3_11 + u*32;
            float row = 0.0f;
            #pragma unroll
            for (int k = 0; k < 32; ++k) row = fmaf(u1i[k], w[k], row);
            acc1 = fmaf(u1i[u], row, acc1);
        }
    }

    out[b] = (acc0 + acc1 * inv_s3) * inv_s2048;
#undef LDSF
}

extern "C" void kernel_launch(void* const* d_in, const int* in_sizes, int n_in,
                              void* d_out, int out_size, void* d_ws, size_t ws_size,
                              hipStream_t stream)
{
    const float* site1   = (const float*)d_in[0];
    const float* site2   = (const float*)d_in[1];
    const float* edge    = (const float*)d_in[2];
    const float* W1_00   = (const float*)d_in[3];
    const float* W1_11_0 = (const float*)d_in[4];
    const float* W1_01   = (const float*)d_in[5];
    const float* W1_10   = (const float*)d_in[6];
    const float* W1_11_1 = (const float*)d_in[7];
    const float* W2_00   = (const float*)d_in[8];
    const float* W2_11_0 = (const float*)d_in[9];
    const float* W2_01   = (const float*)d_in[10];
    const float* W2_10   = (const float*)d_in[11];
    const float* W2_11_1 = (const float*)d_in[12];
    const float* W3_00   = (const float*)d_in[13];
    const float* W3_11   = (const float*)d_in[14];
    float* out = (float*)d_out;

    const int B = in_sizes[0] / 40;
    dim3 grid((B + TPB - 1) / TPB), block(TPB);
    hipLaunchKernelGGL(intersite_fused, grid, block, 0, stream,
                       site1, site2, edge,
                       W1_00, W1_11_0, W1_01, W1_10, W1_11_1,
                       W2_00, W2_11_0, W2_01, W2_10, W2_11_1,
                       W3_00, W3_11, out, B);
}

// Round 4
// 1291.710 us; speedup vs baseline: 1.6714x; 1.6714x over previous
//
#include <hip/hip_runtime.h>

// IntersiteModel fused kernel — fp32 vector, round 6: latency-amortized.
// Post-mortem r5: spill-free (VGPR=88) but VALUBusy=26% -> latency-bound:
// one weight row + one ds_read in flight per rolled iteration (~250cyc stall
// per 64cyc of FMA work). Fix: INVERT NESTING — outer contraction index
// rolled, inner v*k FULLY unrolled (128-512 static FMAs per iter) so the
// compiler batch-issues all of an iteration's s_loads/ds_reads ahead of one
// big FMA block. W3 contractions use 32 PARALLEL accumulators (zs/zv) with
// full static unrolling instead of 32-deep dependent fmaf chains.
// Live sets kept <= ~120 floats at every point (no spills):
//   stage1: t0(32)+t1(48) staged sequentially; stage2a: ua(32)+zs(32);
//   stage2b per-i: g(32)+u1i(32)+zv(32).
// LDS per-thread column (f*128+tid), 80 floats -> 40KB/block, 4 blocks/CU,
// no barriers anywhere (strictly per-thread columns).

#define TPB 128

__device__ __forceinline__ float sigf(float x) {
    return 1.0f / (1.0f + __expf(-x));
}

__global__ __launch_bounds__(TPB, 2)
void intersite_fused(const float* __restrict__ site1,
                     const float* __restrict__ site2,
                     const float* __restrict__ edge,
                     const float* __restrict__ W1_00,
                     const float* __restrict__ W1_11_0,
                     const float* __restrict__ W1_01,
                     const float* __restrict__ W1_10,
                     const float* __restrict__ W1_11_1,
                     const float* __restrict__ W2_00,
                     const float* __restrict__ W2_11_0,
                     const float* __restrict__ W2_01,
                     const float* __restrict__ W2_10,
                     const float* __restrict__ W2_11_1,
                     const float* __restrict__ W3_00,
                     const float* __restrict__ W3_11,
                     float* __restrict__ out, int B)
{
    __shared__ float lds[80 * TPB];
    const int t = threadIdx.x;
    const int b = blockIdx.x * TPB + t;
    if (b >= B) return;   // no barriers anywhere -> early return is safe

#define LDSF(f) lds[(f) * TPB + t]

    const float inv_s3   = 0.57735026918962576f;  // 1/sqrt(3)
    const float inv_s2   = 0.70710678118654752f;  // 1/sqrt(2)
    const float inv_s320 = 0.05590169943749474f;  // 1/sqrt(320)
    const float inv_s192 = 0.07216878364870323f;  // 1/sqrt(192)
    const float inv_s256 = 0.0625f;               // 1/sqrt(256)
    const float inv_s2048= 0.02209708691207961f;  // 1/sqrt(2048)

    // ---------------- stage inputs into LDS ----------------
    // f 0..15 x0 | f 16..39 x1[u*3+i] | f 40..55 y0 | f 56..79 y1[v*3+i]
    {
        const float4* p1 = (const float4*)(site1 + (size_t)b * 40);
        #pragma unroll
        for (int q = 0; q < 10; ++q) {
            float4 r = p1[q];
            LDSF(q*4+0) = r.x; LDSF(q*4+1) = r.y;
            LDSF(q*4+2) = r.z; LDSF(q*4+3) = r.w;
        }
        const float4* p2 = (const float4*)(site2 + (size_t)b * 40);
        #pragma unroll
        for (int q = 0; q < 10; ++q) {
            float4 r = p2[q];
            LDSF(40+q*4+0) = r.x; LDSF(40+q*4+1) = r.y;
            LDSF(40+q*4+2) = r.z; LDSF(40+q*4+3) = r.w;
        }
    }

    // ---------------- stage 1a: t0[32] ----------------
    float t0[32];
    #pragma unroll
    for (int k = 0; k < 32; ++k) t0[k] = 0.0f;

    // W1_00 (16,16,32): outer u rolled, inner v*k unrolled (512 FMA/iter)
    #pragma unroll 1
    for (int u = 0; u < 16; ++u) {
        float xu = LDSF(u);
        const float* wu = W1_00 + u * 512;
        #pragma unroll
        for (int v = 0; v < 16; ++v) {
            float f = xu * LDSF(40 + v);
            #pragma unroll
            for (int k = 0; k < 32; ++k) t0[k] = fmaf(f, wu[v*32+k], t0[k]);
        }
    }
    // W1_11_0 (8,8,32): outer u rolled, inner v*k unrolled (256 FMA/iter)
    #pragma unroll 1
    for (int u = 0; u < 8; ++u) {
        float ax = LDSF(16+u*3), ay = LDSF(17+u*3), az = LDSF(18+u*3);
        const float* wu = W1_11_0 + u * 256;
        #pragma unroll
        for (int v = 0; v < 8; ++v) {
            float d = ax * LDSF(56+v*3);
            d = fmaf(ay, LDSF(57+v*3), d);
            d = fmaf(az, LDSF(58+v*3), d);
            d *= inv_s3;
            #pragma unroll
            for (int k = 0; k < 32; ++k) t0[k] = fmaf(d, wu[v*32+k], t0[k]);
        }
    }
    #pragma unroll
    for (int k = 0; k < 32; ++k) t0[k] *= inv_s320;

    // ---------------- stage 1b: t1[16][3] (t0 parked) ----------------
    float t1[48];
    #pragma unroll
    for (int j = 0; j < 48; ++j) t1[j] = 0.0f;

    // W1_01 (16,8,16): outer u rolled, inner v*k*3 unrolled (384 FMA/iter)
    #pragma unroll 1
    for (int u = 0; u < 16; ++u) {
        float xu = LDSF(u);
        const float* wu = W1_01 + u * 128;
        #pragma unroll
        for (int v = 0; v < 8; ++v) {
            float f0 = xu * LDSF(56+v*3+0);
            float f1 = xu * LDSF(56+v*3+1);
            float f2 = xu * LDSF(56+v*3+2);
            #pragma unroll
            for (int k = 0; k < 16; ++k) {
                float w = wu[v*16+k];
                t1[k*3+0] = fmaf(f0, w, t1[k*3+0]);
                t1[k*3+1] = fmaf(f1, w, t1[k*3+1]);
                t1[k*3+2] = fmaf(f2, w, t1[k*3+2]);
            }
        }
    }
    // W1_10 (8,16,16): outer u rolled, inner v*k*3 unrolled (768 FMA/iter)
    #pragma unroll 1
    for (int u = 0; u < 8; ++u) {
        float ax = LDSF(16+u*3), ay = LDSF(17+u*3), az = LDSF(18+u*3);
        const float* wu = W1_10 + u * 256;
        #pragma unroll
        for (int v = 0; v < 16; ++v) {
            float yv = LDSF(40 + v);
            float f0 = ax*yv, f1 = ay*yv, f2 = az*yv;
            #pragma unroll
            for (int k = 0; k < 16; ++k) {
                float w = wu[v*16+k];
                t1[k*3+0] = fmaf(f0, w, t1[k*3+0]);
                t1[k*3+1] = fmaf(f1, w, t1[k*3+1]);
                t1[k*3+2] = fmaf(f2, w, t1[k*3+2]);
            }
        }
    }
    // W1_11_1 (8,8,16): outer u rolled, inner v*(cross+48 FMA) unrolled
    #pragma unroll 1
    for (int u = 0; u < 8; ++u) {
        float ax = LDSF(16+u*3), ay = LDSF(17+u*3), az = LDSF(18+u*3);
        const float* wu = W1_11_1 + u * 128;
        #pragma unroll
        for (int v = 0; v < 8; ++v) {
            float bx = LDSF(56+v*3), by = LDSF(57+v*3), bz = LDSF(58+v*3);
            float cx = (ay*bz - az*by) * inv_s2;
            float cy = (az*bx - ax*bz) * inv_s2;
            float cz = (ax*by - ay*bx) * inv_s2;
            #pragma unroll
            for (int k = 0; k < 16; ++k) {
                float w = wu[v*16+k];
                t1[k*3+0] = fmaf(cx, w, t1[k*3+0]);
                t1[k*3+1] = fmaf(cy, w, t1[k*3+1]);
                t1[k*3+2] = fmaf(cz, w, t1[k*3+2]);
            }
        }
    }
    #pragma unroll
    for (int j = 0; j < 48; ++j) t1[j] *= inv_s320;

    // handoff: x/y dead; f 0..31 = t0, f 32..79 = t1; t regs die here
    #pragma unroll
    for (int k = 0; k < 32; ++k) LDSF(k) = t0[k];
    #pragma unroll
    for (int j = 0; j < 48; ++j) LDSF(32 + j) = t1[j];

    // ---------------- edge -> regs ----------------
    float e0r[4], e1r[12];
    {
        const float4* pe = (const float4*)(edge + (size_t)b * 16);
        float4 r0 = pe[0], r1 = pe[1], r2 = pe[2], r3 = pe[3];
        e0r[0]=r0.x; e0r[1]=r0.y; e0r[2]=r0.z; e0r[3]=r0.w;
        e1r[0]=r1.x; e1r[1]=r1.y; e1r[2]=r1.z; e1r[3]=r1.w;
        e1r[4]=r2.x; e1r[5]=r2.y; e1r[6]=r2.z; e1r[7]=r2.w;
        e1r[8]=r3.x; e1r[9]=r3.y; e1r[10]=r3.z; e1r[11]=r3.w;
    }

    float acc0 = 0.0f;
    // ---------------- stage 2a: u0 low half -> s -> acc0 ----------------
    {
        float ua[32];
        #pragma unroll
        for (int k = 0; k < 32; ++k) ua[k] = 0.0f;
        // W2_00 (32,4,64), k in [0,32): outer u rolled x2, inner v*k (128 FMA)
        #pragma unroll 2
        for (int u = 0; u < 32; ++u) {
            float tu = LDSF(u);
            const float* wu = W2_00 + u*256;
            #pragma unroll
            for (int v = 0; v < 4; ++v) {
                float f = tu * e0r[v];
                #pragma unroll
                for (int k = 0; k < 32; ++k) ua[k] = fmaf(f, wu[v*64+k], ua[k]);
            }
        }
        // W2_11_0 (16,4,64), k in [0,32)
        #pragma unroll 2
        for (int u = 0; u < 16; ++u) {
            float a0 = LDSF(32+u*3), a1 = LDSF(33+u*3), a2 = LDSF(34+u*3);
            const float* wu = W2_11_0 + u*256;
            #pragma unroll
            for (int v = 0; v < 4; ++v) {
                float d = a0 * e1r[v*3];
                d = fmaf(a1, e1r[v*3+1], d);
                d = fmaf(a2, e1r[v*3+2], d);
                d *= inv_s3;
                #pragma unroll
                for (int k = 0; k < 32; ++k) ua[k] = fmaf(d, wu[v*64+k], ua[k]);
            }
        }
        // s = silu(ua/sqrt192)
        #pragma unroll
        for (int k = 0; k < 32; ++k) {
            float x = ua[k] * inv_s192;
            ua[k] = x * sigf(x);
        }
        // acc0 = s^T W3_00 s : 32 PARALLEL accumulators, full static unroll
        float zs[32];
        #pragma unroll
        for (int k = 0; k < 32; ++k) zs[k] = 0.0f;
        #pragma unroll
        for (int u = 0; u < 32; ++u) {
            const float* w = W3_00 + u*32;
            #pragma unroll
            for (int k = 0; k < 32; ++k) zs[k] = fmaf(ua[u], w[k], zs[k]);
        }
        #pragma unroll
        for (int k = 0; k < 32; ++k) acc0 = fmaf(zs[k], ua[k], acc0);
    }

    // ---------------- stage 2a': u0 high half -> g[32] ----------------
    float g[32];
    {
        float ub[32];
        #pragma unroll
        for (int k = 0; k < 32; ++k) ub[k] = 0.0f;
        #pragma unroll 2
        for (int u = 0; u < 32; ++u) {
            float tu = LDSF(u);
            const float* wu = W2_00 + u*256 + 32;
            #pragma unroll
            for (int v = 0; v < 4; ++v) {
                float f = tu * e0r[v];
                #pragma unroll
                for (int k = 0; k < 32; ++k) ub[k] = fmaf(f, wu[v*64+k], ub[k]);
            }
        }
        #pragma unroll 2
        for (int u = 0; u < 16; ++u) {
            float a0 = LDSF(32+u*3), a1 = LDSF(33+u*3), a2 = LDSF(34+u*3);
            const float* wu = W2_11_0 + u*256 + 32;
            #pragma unroll
            for (int v = 0; v < 4; ++v) {
                float d = a0 * e1r[v*3];
                d = fmaf(a1, e1r[v*3+1], d);
                d = fmaf(a2, e1r[v*3+2], d);
                d *= inv_s3;
                #pragma unroll
                for (int k = 0; k < 32; ++k) ub[k] = fmaf(d, wu[v*64+k], ub[k]);
            }
        }
        #pragma unroll
        for (int k = 0; k < 32; ++k) g[k] = sigf(ub[k] * inv_s192);
    }

    // ---------------- stage 2b+3: per-component u1_i -> gate -> acc1 -------
    // rolled i-loop; e1 components re-loaded from global per pass (L1-hot)
    // so no register array is ever runtime-indexed.
    float acc1 = 0.0f;
    const float* ep = edge + (size_t)b * 16 + 4;
    #pragma unroll 1
    for (int i = 0; i < 3; ++i) {
        int jj = (i == 2) ? 0 : i + 1;
        int kk = (jj == 2) ? 0 : jj + 1;
        float e1i[4], e1j[4], e1k[4];
        #pragma unroll
        for (int v = 0; v < 4; ++v) {
            e1i[v] = ep[v*3 + i];
            e1j[v] = ep[v*3 + jj];
            e1k[v] = ep[v*3 + kk];
        }
        float u1i[32];
        #pragma unroll
        for (int k = 0; k < 32; ++k) u1i[k] = 0.0f;

        // W2_01 (32,4,32): u1_i[w] += t0[u] e1[v,i] W[u,v,w]
        #pragma unroll 2
        for (int u = 0; u < 32; ++u) {
            float tu = LDSF(u);
            const float* wu = W2_01 + u*128;
            #pragma unroll
            for (int v = 0; v < 4; ++v) {
                float f = tu * e1i[v];
                #pragma unroll
                for (int k = 0; k < 32; ++k) u1i[k] = fmaf(f, wu[v*32+k], u1i[k]);
            }
        }
        // W2_10 (16,4,32): u1_i[w] += t1[u,i] e0[v] W[u,v,w]
        #pragma unroll 2
        for (int u = 0; u < 16; ++u) {
            float ai = LDSF(32 + u*3 + i);
            const float* wu = W2_10 + u*128;
            #pragma unroll
            for (int v = 0; v < 4; ++v) {
                float f = ai * e0r[v];
                #pragma unroll
                for (int k = 0; k < 32; ++k) u1i[k] = fmaf(f, wu[v*32+k], u1i[k]);
            }
        }
        // W2_11_1 (16,4,32): u1_i[w] += (t1[u] x e1[v])_i /sqrt2 W[u,v,w]
        #pragma unroll 2
        for (int u = 0; u < 16; ++u) {
            float aj = LDSF(32 + u*3 + jj);
            float ak = LDSF(32 + u*3 + kk);
            const float* wu = W2_11_1 + u*128;
            #pragma unroll
            for (int v = 0; v < 4; ++v) {
                float c = (aj * e1k[v] - ak * e1j[v]) * inv_s2;
                #pragma unroll
                for (int k = 0; k < 32; ++k) u1i[k] = fmaf(c, wu[v*32+k], u1i[k]);
            }
        }
        // gate: v_i = (u1_i/sqrt256) * g ; acc1 += v_i^T W3_11 v_i
        #pragma unroll
        for (int k = 0; k < 32; ++k) u1i[k] = u1i[k] * inv_s256 * g[k];
        float zv[32];
        #pragma unroll
        for (int k = 0; k < 32; ++k) zv[k] = 0.0f;
        #pragma unroll
        for (int u = 0; u < 32; ++u) {
            const float* w = W3_11 + u*32;
            #pragma unroll
            for (int k = 0; k < 32; ++k) zv[k] = fmaf(u1i[u], w[k], zv[k]);
        }
        #pragma unroll
        for (int k = 0; k < 32; ++k) acc1 = fmaf(zv[k], u1i[k], acc1);
    }

    out[b] = (acc0 + acc1 * inv_s3) * inv_s2048;
#undef LDSF
}

extern "C" void kernel_launch(void* const* d_in, const int* in_sizes, int n_in,
                              void* d_out, int out_size, void* d_ws, size_t ws_size,
                              hipStream_t stream)
{
    const float* site1   = (const float*)d_in[0];
    const float* site2   = (const float*)d_in[1];
    const float* edge    = (const float*)d_in[2];
    const float* W1_00   = (const float*)d_in[3];
    const float* W1_11_0 = (const float*)d_in[4];
    const float* W1_01   = (const float*)d_in[5];
    const float* W1_10   = (const float*)d_in[6];
    const float* W1_11_1 = (const float*)d_in[7];
    const float* W2_00   = (const float*)d_in[8];
    const float* W2_11_0 = (const float*)d_in[9];
    const float* W2_01   = (const float*)d_in[10];
    const float* W2_10   = (const float*)d_in[11];
    const float* W2_11_1 = (const float*)d_in[12];
    const float* W3_00   = (const float*)d_in[13];
    const float* W3_11   = (const float*)d_in[14];
    float* out = (float*)d_out;

    const int B = in_sizes[0] / 40;
    dim3 grid((B + TPB - 1) / TPB), block(TPB);
    hipLaunchKernelGGL(intersite_fused, grid, block, 0, stream,
                       site1, site2, edge,
                       W1_00, W1_11_0, W1_01, W1_10, W1_11_1,
                       W2_00, W2_11_0, W2_01, W2_10, W2_11_1,
                       W3_00, W3_11, out, B);
}